// Round 7
// baseline (189.182 us; speedup 1.0000x reference)
//
#include <hip/hip_runtime.h>
#include <hip/hip_bf16.h>
#include <math.h>

#define D_MODEL 768
#define NHEADS  12
#define DHEAD   64
#define NQR     8     // query rows
#define BB      16    // batch (ranks)
#define PP      197   // tokens per rank
#define NPAIR   256   // BB*BB
#define MKV     (BB*PP)     // 3152
#define LN_EPSF 1e-5f
#define SCALEF  0.125f      // 64^-0.5

// split-bf16 K-extended GEMM params
#define KTOT  2304          // 3*768:  [a_hi|a_hi|a_lo] x [w_hi|w_lo|w_hi]
#define KSPLIT 3
#define KPER  (KTOT/KSPLIT) // 768
#define MPAD  3200          // 25*128
#define BM 128
#define BN 128
#define BK 64

typedef __attribute__((ext_vector_type(8))) short short8v;   // 8 bf16
typedef __attribute__((ext_vector_type(4))) float float4v;   // mfma acc

__device__ __forceinline__ void gload16(const void* g, void* l){
  __builtin_amdgcn_global_load_lds(
      (const __attribute__((address_space(1))) unsigned int*)g,
      (__attribute__((address_space(3))) unsigned int*)l, 16, 0, 0);
}

// ---------------------------------------------------------------------------
// q GEMM: qy[8,768] = qx[8,768] @ qw[768,768]^T
// 96 blocks x 256 thr; 8 cols/block x 32 lanes/col (coalesced w-row reads).
// NOTE (R5 post-mortem): do NOT replace with per-thread serial dot.
// ---------------------------------------------------------------------------
__global__ __launch_bounds__(256) void qgemm_kernel(
    const float* __restrict__ qx, const float* __restrict__ qw,
    float* __restrict__ qy)
{
  __shared__ float xs[NQR*D_MODEL];
  int tid = threadIdx.x;
  for (int e = tid*4; e < NQR*D_MODEL; e += 1024)
    *(float4*)&xs[e] = *(const float4*)&qx[e];
  __syncthreads();
  int col = tid >> 5, lane = tid & 31;
  int c = blockIdx.x*8 + col;
  const float* wr = qw + (size_t)c*D_MODEL;
  float acc[NQR] = {};
  for (int k = lane*4; k < D_MODEL; k += 128){
    float4 w4 = *(const float4*)&wr[k];
    #pragma unroll
    for (int q = 0; q < NQR; q++){
      float4 x4 = *(const float4*)&xs[q*D_MODEL + k];
      acc[q] += x4.x*w4.x + x4.y*w4.y + x4.z*w4.z + x4.w*w4.w;
    }
  }
  #pragma unroll
  for (int q = 0; q < NQR; q++){
    float a = acc[q];
    for (int off = 16; off >= 1; off >>= 1) a += __shfl_xor(a, off, 32);
    if (lane == 0) qy[q*D_MODEL + c] = a;
  }
}

// ---------------------------------------------------------------------------
// LN over y+bias (q path, 8 rows)
// ---------------------------------------------------------------------------
__global__ __launch_bounds__(256) void ln_rows_kernel(
    const float* __restrict__ Y, const float* __restrict__ bias,
    const float* __restrict__ lnw, const float* __restrict__ lnb,
    float* __restrict__ out)
{
  __shared__ float red[256], red2[256];
  int r = blockIdx.x, tid = threadIdx.x;
  const float* yr = Y + (size_t)r*D_MODEL;
  float x0 = yr[tid      ] + bias[tid      ];
  float x1 = yr[tid + 256] + bias[tid + 256];
  float x2 = yr[tid + 512] + bias[tid + 512];
  red[tid] = x0 + x1 + x2; red2[tid] = x0*x0 + x1*x1 + x2*x2;
  __syncthreads();
  for (int st = 128; st > 0; st >>= 1){
    if (tid < st){ red[tid] += red[tid+st]; red2[tid] += red2[tid+st]; }
    __syncthreads();
  }
  float mean = red[0]*(1.f/768.f);
  float var  = red2[0]*(1.f/768.f) - mean*mean;
  float inv  = rsqrtf(var + LN_EPSF);
  float* orow = out + (size_t)r*D_MODEL;
  orow[tid      ] = (x0-mean)*inv*lnw[tid      ] + lnb[tid      ];
  orow[tid + 256] = (x1-mean)*inv*lnw[tid + 256] + lnb[tid + 256];
  orow[tid + 512] = (x2-mean)*inv*lnw[tid + 512] + lnb[tid + 512];
}

// ---------------------------------------------------------------------------
// fused pack: f32 row [768] -> bf16 row [2304] as three 768-segments.
// ---------------------------------------------------------------------------
__global__ __launch_bounds__(192) void pack_both_kernel(
    const float* __restrict__ kvx, const float* __restrict__ kvw,
    __hip_bfloat16* __restrict__ Ab, __hip_bfloat16* __restrict__ Wb)
{
  int b = blockIdx.x, t = threadIdx.x;
  const float* X; __hip_bfloat16* Y; int valid, mode, m;
  if (b < MPAD){ X = kvx; Y = Ab; valid = MKV;     mode = 0; m = b; }
  else         { X = kvw; Y = Wb; valid = D_MODEL; mode = 1; m = b - MPAD; }
  int k = t*4;
  float4 v = (m < valid) ? *(const float4*)&X[(size_t)m*D_MODEL + k]
                         : make_float4(0.f,0.f,0.f,0.f);
  float xsv[4] = {v.x, v.y, v.z, v.w};
  unsigned short hu[4], lu[4];
  #pragma unroll
  for (int i = 0; i < 4; i++){
    __hip_bfloat16 h = __float2bfloat16(xsv[i]);
    float hf = __bfloat162float(h);
    __hip_bfloat16 l = __float2bfloat16(xsv[i] - hf);
    hu[i] = *(unsigned short*)&h;
    lu[i] = *(unsigned short*)&l;
  }
  ushort4 hv = {hu[0], hu[1], hu[2], hu[3]};
  ushort4 lv = {lu[0], lu[1], lu[2], lu[3]};
  ushort4* row = (ushort4*)(Y + (size_t)m*KTOT);
  int s = k >> 2;
  if (mode == 0){ row[s] = hv; row[s+192] = hv; row[s+384] = lv; }
  else          { row[s] = hv; row[s+192] = lv; row[s+384] = hv; }
}

// ---------------------------------------------------------------------------
// bf16 MFMA GEMM: C[kt][m][n] partial over K-split (kt = 0..2).
// ---------------------------------------------------------------------------
__global__ __launch_bounds__(256) void gemm_mfma_kernel(
    const __hip_bfloat16* __restrict__ Ab, const __hip_bfloat16* __restrict__ Wb,
    float* __restrict__ Cp)
{
  __shared__ __hip_bfloat16 As[BM*BK];   // 16 KB
  __shared__ __hip_bfloat16 Bs[BN*BK];   // 16 KB
  int tid = threadIdx.x;
  int wave = tid >> 6, lane = tid & 63;
  int m0 = blockIdx.x*BM, n0 = blockIdx.y*BN, kt = blockIdx.z;
  int wr = wave >> 1, wc = wave & 1;

  float4v acc[4][4];
  #pragma unroll
  for (int i = 0; i < 4; i++)
    #pragma unroll
    for (int j = 0; j < 4; j++)
      acc[i][j] = (float4v){0.f, 0.f, 0.f, 0.f};

  int sbase = wave*256;
  for (int st = 0; st < KPER/BK; ++st){
    int k0 = kt*KPER + st*BK;
    __syncthreads();
    #pragma unroll
    for (int i = 0; i < 4; i++){
      int s  = sbase + i*64 + lane;
      int r  = s >> 3, kg = s & 7;
      int kgg = kg ^ (r & 7);
      gload16(Ab + (size_t)(m0 + r)*KTOT + k0 + kgg*8, (char*)As + (size_t)s*16);
      gload16(Wb + (size_t)(n0 + r)*KTOT + k0 + kgg*8, (char*)Bs + (size_t)s*16);
    }
    __syncthreads();
    #pragma unroll
    for (int ks = 0; ks < 2; ks++){
      int kq = ks*4 + (lane >> 4);
      short8v af[4], bf[4];
      #pragma unroll
      for (int t = 0; t < 4; t++){
        int ar = wr*64 + t*16 + (lane & 15);
        int as_ = ar*8 + (kq ^ (ar & 7));
        af[t] = *(const short8v*)((const char*)As + (size_t)as_*16);
        int br = wc*64 + t*16 + (lane & 15);
        int bs_ = br*8 + (kq ^ (br & 7));
        bf[t] = *(const short8v*)((const char*)Bs + (size_t)bs_*16);
      }
      #pragma unroll
      for (int i = 0; i < 4; i++)
        #pragma unroll
        for (int j = 0; j < 4; j++)
          acc[i][j] = __builtin_amdgcn_mfma_f32_16x16x32_bf16(af[i], bf[j], acc[i][j], 0, 0, 0);
    }
  }

  float* C = Cp + (size_t)kt*MKV*D_MODEL;
  #pragma unroll
  for (int i = 0; i < 4; i++){
    int mb = m0 + wr*64 + i*16 + ((lane >> 4) << 2);
    #pragma unroll
    for (int j = 0; j < 4; j++){
      int n = n0 + wc*64 + j*16 + (lane & 15);
      #pragma unroll
      for (int r = 0; r < 4; r++){
        int m = mb + r;
        if (m < MKV) C[(size_t)m*D_MODEL + n] = acc[i][j][r];
      }
    }
  }
}

// ---------------------------------------------------------------------------
// LN over y0+y1+y2+bias (sums the 3 split-K GEMM partials)
// ---------------------------------------------------------------------------
__global__ __launch_bounds__(256) void ln_rows3_kernel(
    const float* __restrict__ Y0, const float* __restrict__ Y1,
    const float* __restrict__ Y2, const float* __restrict__ bias,
    const float* __restrict__ lnw, const float* __restrict__ lnb,
    float* __restrict__ out)
{
  __shared__ float red[256], red2[256];
  int r = blockIdx.x, tid = threadIdx.x;
  const float* y0 = Y0 + (size_t)r*D_MODEL;
  const float* y1 = Y1 + (size_t)r*D_MODEL;
  const float* y2 = Y2 + (size_t)r*D_MODEL;
  float x0 = y0[tid      ] + y1[tid      ] + y2[tid      ] + bias[tid      ];
  float x1 = y0[tid + 256] + y1[tid + 256] + y2[tid + 256] + bias[tid + 256];
  float x2 = y0[tid + 512] + y1[tid + 512] + y2[tid + 512] + bias[tid + 512];
  red[tid] = x0 + x1 + x2; red2[tid] = x0*x0 + x1*x1 + x2*x2;
  __syncthreads();
  for (int st = 128; st > 0; st >>= 1){
    if (tid < st){ red[tid] += red[tid+st]; red2[tid] += red2[tid+st]; }
    __syncthreads();
  }
  float mean = red[0]*(1.f/768.f);
  float var  = red2[0]*(1.f/768.f) - mean*mean;
  float inv  = rsqrtf(var + LN_EPSF);
  float* orow = out + (size_t)r*D_MODEL;
  orow[tid      ] = (x0-mean)*inv*lnw[tid      ] + lnb[tid      ];
  orow[tid + 256] = (x1-mean)*inv*lnw[tid + 256] + lnb[tid + 256];
  orow[tid + 512] = (x2-mean)*inv*lnw[tid + 512] + lnb[tid + 512];
}

// ---------------------------------------------------------------------------
// Per-(rank, head, HALF) attention partials + out_w projection (restructured):
//  - one block per half (grid 16x12x2 = 384) -> all CUs busy, half the serial
//  - A stored TRANSPOSED: AT[d][p], row stride 256 floats, 16B-block xor
//    swizzle (pblock ^= d&7) -> U-loop reads are conflict-free ds_read_b128
//  - E rows padded to 208 floats (16B-aligned b128 broadcast reads)
// LDS: AT 64 KB + qs 2 KB + E 6.5 KB + Us 2 KB = 74.5 KB -> 2 blocks/CU.
// ---------------------------------------------------------------------------
#define ATS 256   // AT row stride (floats)
#define EPS_ 208  // E row stride (floats)
__device__ __forceinline__ int at_idx(int d, int p){
  return d*ATS + ((((p >> 2) ^ (d & 7)) << 2) | (p & 3));
}

__global__ __launch_bounds__(256) void rank_proj_kernel(
    const float* __restrict__ kv_ln, const float* __restrict__ q_ln,
    const float* __restrict__ ppe, const float* __restrict__ ow,
    float* __restrict__ m1O, float* __restrict__ z1O,
    float* __restrict__ m2O, float* __restrict__ z2O,
    float* __restrict__ p1, float* __restrict__ p2)
{
  __shared__ float AT[64*ATS];     // 64 KB (swizzled transpose)
  __shared__ float qs[NQR*64];     //  2 KB
  __shared__ float E[NQR*EPS_];    //  6.5 KB
  __shared__ float Us[NQR*64];     //  2 KB
  int r = blockIdx.x, h = blockIdx.y, half = blockIdx.z;
  int tid = threadIdx.x;

  for (int e = tid; e < NQR*64; e += 256){
    int q = e >> 6, d = e & 63;
    qs[e] = q_ln[q*D_MODEL + h*64 + d];
  }
  // stage A^T (cols 197..199 zeroed so the b128 U-loop tail is clean)
  for (int e = tid; e < 200*64; e += 256){
    int p = e >> 6, d = e & 63;
    float v = 0.f;
    if (p < PP)
      v = kv_ln[((size_t)(r*PP + p))*D_MODEL + h*64 + d]
        + ppe[((size_t)(half*PP + p))*D_MODEL + h*64 + d];
    AT[at_idx(d, p)] = v;
  }
  __syncthreads();

  int q = tid >> 5, sub = tid & 31;
  // ---- scores: s[q,p] = SCALE * <qs[q,:], A[p,:]>  (lanes over p) ----
  float s[7];
  #pragma unroll
  for (int i = 0; i < 7; i++) s[i] = 0.f;
  for (int d = 0; d < 64; d++){
    float qv = qs[q*64 + d];
    #pragma unroll
    for (int i = 0; i < 7; i++){
      int p = sub + 32*i;
      int pc = p < PP ? p : PP-1;
      s[i] += qv * AT[at_idx(d, pc)];
    }
  }
  float mloc = -1e30f;
  #pragma unroll
  for (int i = 0; i < 7; i++){
    int p = sub + 32*i;
    s[i] = (p < PP) ? s[i]*SCALEF : -1e30f;
    mloc = fmaxf(mloc, s[i]);
  }
  for (int off = 16; off >= 1; off >>= 1)
    mloc = fmaxf(mloc, __shfl_xor(mloc, off, 32));
  float zloc = 0.f;
  #pragma unroll
  for (int i = 0; i < 7; i++){
    int p = sub + 32*i;
    float e = __expf(s[i] - mloc);
    if (p < PP){ E[q*EPS_ + p] = e; zloc += e; }
    else if (p < 200){ E[q*EPS_ + p] = 0.f; }
  }
  for (int off = 16; off >= 1; off >>= 1)
    zloc += __shfl_xor(zloc, off, 32);

  int idx = (r*NHEADS + h)*NQR + q;
  if (sub == 0){
    if (half){ m2O[idx] = mloc; z2O[idx] = zloc; }
    else     { m1O[idx] = mloc; z1O[idx] = zloc; }
  }
  // E/AT visible within the q-group's own wave; no barrier needed before U.

  // ---- U[q][d] = sum_p E[q][p]*A[p][d]  (lane owns d=sub, sub+32) ----
  float u0 = 0.f, u1 = 0.f;
  int sw = (sub & 7);
  for (int p4 = 0; p4 < 200; p4 += 4){
    float4 e4 = *(const float4*)&E[q*EPS_ + p4];
    int cb = (((p4 >> 2) ^ sw) << 2);
    float4 a0 = *(const float4*)&AT[sub*ATS + cb];
    float4 a1 = *(const float4*)&AT[(sub+32)*ATS + cb];
    u0 += e4.x*a0.x + e4.y*a0.y + e4.z*a0.z + e4.w*a0.w;
    u1 += e4.x*a1.x + e4.y*a1.y + e4.z*a1.z + e4.w*a1.w;
  }
  Us[q*64 + sub]      = u0;
  Us[q*64 + sub + 32] = u1;
  __syncthreads();

  // ---- projection: P[q][n] = sum_d Us[q][d] * ow[n][h*64+d] ----
  float acc[NQR][3];
  #pragma unroll
  for (int m = 0; m < NQR; m++){ acc[m][0]=0.f; acc[m][1]=0.f; acc[m][2]=0.f; }
  const float* owh = ow + h*64;
  for (int d4 = 0; d4 < 64; d4 += 4){
    float4 w0 = *(const float4*)&owh[(size_t)(tid      )*D_MODEL + d4];
    float4 w1 = *(const float4*)&owh[(size_t)(tid + 256)*D_MODEL + d4];
    float4 w2 = *(const float4*)&owh[(size_t)(tid + 512)*D_MODEL + d4];
    #pragma unroll
    for (int m = 0; m < NQR; m++){
      float4 u = *(const float4*)&Us[m*64 + d4];
      acc[m][0] += u.x*w0.x + u.y*w0.y + u.z*w0.z + u.w*w0.w;
      acc[m][1] += u.x*w1.x + u.y*w1.y + u.z*w1.z + u.w*w1.w;
      acc[m][2] += u.x*w2.x + u.y*w2.y + u.z*w2.z + u.w*w2.w;
    }
  }
  float* P = half ? p2 : p1;
  #pragma unroll
  for (int m = 0; m < NQR; m++){
    size_t base = (((size_t)r*NHEADS + h)*NQR + m)*D_MODEL;
    #pragma unroll
    for (int j = 0; j < 3; j++)
      P[base + tid + 256*j] = acc[m][j];
  }
}

// ---------------------------------------------------------------------------
// Final combine:
//   out[(i*16+j)*8+q, n] = sum_h c1[h]*P1[i,h,q,n] - c2[h]*P2[j,h,q,n] + out_b[n]
// ---------------------------------------------------------------------------
__global__ __launch_bounds__(256) void combine_out_kernel(
    const float* __restrict__ m1, const float* __restrict__ z1,
    const float* __restrict__ m2, const float* __restrict__ z2,
    const float* __restrict__ p1, const float* __restrict__ p2,
    const float* __restrict__ out_b, float* __restrict__ out)
{
  __shared__ float c1s[NHEADS], c2s[NHEADS];
  int pair = blockIdx.x, q = blockIdx.y, tid = threadIdx.x;
  int i = pair >> 4, j = pair & 15;
  if (tid < NHEADS){
    int h = tid;
    int ii = (i*NHEADS + h)*NQR + q;
    int jj = (j*NHEADS + h)*NQR + q;
    float mi = m1[ii], mj = m2[jj];
    float mm = fmaxf(mi, mj);
    float a1 = __expf(mi - mm), a2 = __expf(mj - mm);
    float rden = 1.f / (a1*z1[ii] + a2*z2[jj]);
    c1s[h] = a1*rden; c2s[h] = a2*rden;
  }
  __syncthreads();
  float* orow = out + ((size_t)(pair*NQR + q))*D_MODEL;
  for (int nn = tid; nn < D_MODEL; nn += 256){
    float acc = out_b[nn];
    #pragma unroll
    for (int h = 0; h < NHEADS; h++){
      acc += c1s[h]*p1[(((size_t)i*NHEADS + h)*NQR + q)*D_MODEL + nn]
           - c2s[h]*p2[(((size_t)j*NHEADS + h)*NQR + q)*D_MODEL + nn];
    }
    orow[nn] = acc;
  }
}

// ---------------------------------------------------------------------------
extern "C" void kernel_launch(void* const* d_in, const int* in_sizes, int n_in,
                              void* d_out, int out_size, void* d_ws, size_t ws_size,
                              hipStream_t stream)
{
  const float* q_x    = (const float*)d_in[0];
  const float* kv_x   = (const float*)d_in[1];
  const float* ppe    = (const float*)d_in[2];
  const float* q_w    = (const float*)d_in[3];
  const float* q_b    = (const float*)d_in[4];
  const float* kv_w   = (const float*)d_in[5];
  const float* kv_b   = (const float*)d_in[6];
  const float* out_w  = (const float*)d_in[7];
  const float* out_b  = (const float*)d_in[8];
  const float* lnq_w  = (const float*)d_in[9];
  const float* lnq_b  = (const float*)d_in[10];
  const float* lnkv_w = (const float*)d_in[11];
  const float* lnkv_b = (const float*)d_in[12];
  float* out = (float*)d_out;

  float* ws    = (float*)d_ws;
  float* q_y   = ws;                              //  6144
  float* q_ln  = q_y  + NQR*D_MODEL;              //  6144
  float* Abuf_f = q_ln + NQR*D_MODEL;             //  3,686,400 (3200*2304 bf16)
  float* Wbuf_f = Abuf_f + (size_t)MPAD*KTOT/2;   //    884,736 (768*2304 bf16)
  float* C0    = Wbuf_f + (size_t)D_MODEL*KTOT/2; //  3x 2,420,736
  float* C1    = C0 + (size_t)MKV*D_MODEL;
  float* C2    = C1 + (size_t)MKV*D_MODEL;

  __hip_bfloat16* Abuf = (__hip_bfloat16*)Abuf_f;
  __hip_bfloat16* Wbuf = (__hip_bfloat16*)Wbuf_f;

  float* kv_ln = Abuf_f;                          // alias (2,420,736 <= 3,686,400)
  float* m1    = Wbuf_f;                          // alias region (6,144 <= 884,736)
  float* z1    = m1 + BB*NHEADS*NQR;
  float* m2    = z1 + BB*NHEADS*NQR;
  float* z2    = m2 + BB*NHEADS*NQR;
  float* p1    = C0;                              // alias (2,359,296 <= 7,262,208)
  float* p2    = p1 + (size_t)BB*NHEADS*NQR*D_MODEL;

  qgemm_kernel<<<96, 256, 0, stream>>>(q_x, q_w, q_y);
  ln_rows_kernel<<<NQR, 256, 0, stream>>>(q_y, q_b, lnq_w, lnq_b, q_ln);

  pack_both_kernel<<<MPAD + D_MODEL, 192, 0, stream>>>(kv_x, kv_w, Abuf, Wbuf);

  gemm_mfma_kernel<<<dim3(MPAD/BM, D_MODEL/BN, KSPLIT), 256, 0, stream>>>(
      Abuf, Wbuf, C0);

  ln_rows3_kernel<<<MKV, 256, 0, stream>>>(C0, C1, C2, kv_b, lnkv_w, lnkv_b, kv_ln);

  rank_proj_kernel<<<dim3(BB, NHEADS, 2), 256, 0, stream>>>(
      kv_ln, q_ln, ppe, out_w, m1, z1, m2, z2, p1, p2);

  combine_out_kernel<<<dim3(NPAIR, NQR), 256, 0, stream>>>(
      m1, z1, m2, z2, p1, p2, out_b, out);
}

// Round 8
// 178.487 us; speedup vs baseline: 1.0599x; 1.0599x over previous
//
#include <hip/hip_runtime.h>
#include <hip/hip_bf16.h>
#include <math.h>

#define D_MODEL 768
#define NHEADS  12
#define DHEAD   64
#define NQR     8     // query rows
#define BB      16    // batch (ranks)
#define PP      197   // tokens per rank
#define NPAIR   256   // BB*BB
#define MKV     (BB*PP)     // 3152
#define LN_EPSF 1e-5f
#define SCALEF  0.125f      // 64^-0.5

// split-bf16 K-extended GEMM params
#define KTOT  2304          // 3*768:  [a_hi|a_hi|a_lo] x [w_hi|w_lo|w_hi]
#define KSPLIT 3
#define KPER  (KTOT/KSPLIT) // 768
#define MPAD  3200          // 25*128
#define BM 128
#define BN 128
#define BK 64

// attention p-chunking (occupancy: 768 blocks, ~31 KB LDS -> 3 blocks/CU)
#define NCHUNK 2
#define CH0    100          // chunk 0: p in [0,100)
#define CH1    97           // chunk 1: p in [100,197)
#define CHMAX  100
#define EROW   104          // E row stride
#define NIDX   (BB*NHEADS*2*NQR)   // 3072 partial slots

typedef __attribute__((ext_vector_type(8))) short short8v;   // 8 bf16
typedef __attribute__((ext_vector_type(4))) float float4v;   // mfma acc

__device__ __forceinline__ void gload16(const void* g, void* l){
  __builtin_amdgcn_global_load_lds(
      (const __attribute__((address_space(1))) unsigned int*)g,
      (__attribute__((address_space(3))) unsigned int*)l, 16, 0, 0);
}

// ---------------------------------------------------------------------------
// q GEMM: qy[8,768] = qx[8,768] @ qw[768,768]^T
// NOTE (R5 post-mortem): do NOT replace with per-thread serial dot.
// ---------------------------------------------------------------------------
__global__ __launch_bounds__(256) void qgemm_kernel(
    const float* __restrict__ qx, const float* __restrict__ qw,
    float* __restrict__ qy)
{
  __shared__ float xs[NQR*D_MODEL];
  int tid = threadIdx.x;
  for (int e = tid*4; e < NQR*D_MODEL; e += 1024)
    *(float4*)&xs[e] = *(const float4*)&qx[e];
  __syncthreads();
  int col = tid >> 5, lane = tid & 31;
  int c = blockIdx.x*8 + col;
  const float* wr = qw + (size_t)c*D_MODEL;
  float acc[NQR] = {};
  for (int k = lane*4; k < D_MODEL; k += 128){
    float4 w4 = *(const float4*)&wr[k];
    #pragma unroll
    for (int q = 0; q < NQR; q++){
      float4 x4 = *(const float4*)&xs[q*D_MODEL + k];
      acc[q] += x4.x*w4.x + x4.y*w4.y + x4.z*w4.z + x4.w*w4.w;
    }
  }
  #pragma unroll
  for (int q = 0; q < NQR; q++){
    float a = acc[q];
    for (int off = 16; off >= 1; off >>= 1) a += __shfl_xor(a, off, 32);
    if (lane == 0) qy[q*D_MODEL + c] = a;
  }
}

// ---------------------------------------------------------------------------
// LN over y+bias (q path, 8 rows)
// ---------------------------------------------------------------------------
__global__ __launch_bounds__(256) void ln_rows_kernel(
    const float* __restrict__ Y, const float* __restrict__ bias,
    const float* __restrict__ lnw, const float* __restrict__ lnb,
    float* __restrict__ out)
{
  __shared__ float red[256], red2[256];
  int r = blockIdx.x, tid = threadIdx.x;
  const float* yr = Y + (size_t)r*D_MODEL;
  float x0 = yr[tid      ] + bias[tid      ];
  float x1 = yr[tid + 256] + bias[tid + 256];
  float x2 = yr[tid + 512] + bias[tid + 512];
  red[tid] = x0 + x1 + x2; red2[tid] = x0*x0 + x1*x1 + x2*x2;
  __syncthreads();
  for (int st = 128; st > 0; st >>= 1){
    if (tid < st){ red[tid] += red[tid+st]; red2[tid] += red2[tid+st]; }
    __syncthreads();
  }
  float mean = red[0]*(1.f/768.f);
  float var  = red2[0]*(1.f/768.f) - mean*mean;
  float inv  = rsqrtf(var + LN_EPSF);
  float* orow = out + (size_t)r*D_MODEL;
  orow[tid      ] = (x0-mean)*inv*lnw[tid      ] + lnb[tid      ];
  orow[tid + 256] = (x1-mean)*inv*lnw[tid + 256] + lnb[tid + 256];
  orow[tid + 512] = (x2-mean)*inv*lnw[tid + 512] + lnb[tid + 512];
}

// ---------------------------------------------------------------------------
// fused pack: f32 row [768] -> bf16 row [2304] as three 768-segments.
// ---------------------------------------------------------------------------
__global__ __launch_bounds__(192) void pack_both_kernel(
    const float* __restrict__ kvx, const float* __restrict__ kvw,
    __hip_bfloat16* __restrict__ Ab, __hip_bfloat16* __restrict__ Wb)
{
  int b = blockIdx.x, t = threadIdx.x;
  const float* X; __hip_bfloat16* Y; int valid, mode, m;
  if (b < MPAD){ X = kvx; Y = Ab; valid = MKV;     mode = 0; m = b; }
  else         { X = kvw; Y = Wb; valid = D_MODEL; mode = 1; m = b - MPAD; }
  int k = t*4;
  float4 v = (m < valid) ? *(const float4*)&X[(size_t)m*D_MODEL + k]
                         : make_float4(0.f,0.f,0.f,0.f);
  float xsv[4] = {v.x, v.y, v.z, v.w};
  unsigned short hu[4], lu[4];
  #pragma unroll
  for (int i = 0; i < 4; i++){
    __hip_bfloat16 h = __float2bfloat16(xsv[i]);
    float hf = __bfloat162float(h);
    __hip_bfloat16 l = __float2bfloat16(xsv[i] - hf);
    hu[i] = *(unsigned short*)&h;
    lu[i] = *(unsigned short*)&l;
  }
  ushort4 hv = {hu[0], hu[1], hu[2], hu[3]};
  ushort4 lv = {lu[0], lu[1], lu[2], lu[3]};
  ushort4* row = (ushort4*)(Y + (size_t)m*KTOT);
  int s = k >> 2;
  if (mode == 0){ row[s] = hv; row[s+192] = hv; row[s+384] = lv; }
  else          { row[s] = hv; row[s+192] = lv; row[s+384] = hv; }
}

// ---------------------------------------------------------------------------
// bf16 MFMA GEMM: C[kt][m][n] partial over K-split (kt = 0..2).
// ---------------------------------------------------------------------------
__global__ __launch_bounds__(256) void gemm_mfma_kernel(
    const __hip_bfloat16* __restrict__ Ab, const __hip_bfloat16* __restrict__ Wb,
    float* __restrict__ Cp)
{
  __shared__ __hip_bfloat16 As[BM*BK];   // 16 KB
  __shared__ __hip_bfloat16 Bs[BN*BK];   // 16 KB
  int tid = threadIdx.x;
  int wave = tid >> 6, lane = tid & 63;
  int m0 = blockIdx.x*BM, n0 = blockIdx.y*BN, kt = blockIdx.z;
  int wr = wave >> 1, wc = wave & 1;

  float4v acc[4][4];
  #pragma unroll
  for (int i = 0; i < 4; i++)
    #pragma unroll
    for (int j = 0; j < 4; j++)
      acc[i][j] = (float4v){0.f, 0.f, 0.f, 0.f};

  int sbase = wave*256;
  for (int st = 0; st < KPER/BK; ++st){
    int k0 = kt*KPER + st*BK;
    __syncthreads();
    #pragma unroll
    for (int i = 0; i < 4; i++){
      int s  = sbase + i*64 + lane;
      int r  = s >> 3, kg = s & 7;
      int kgg = kg ^ (r & 7);
      gload16(Ab + (size_t)(m0 + r)*KTOT + k0 + kgg*8, (char*)As + (size_t)s*16);
      gload16(Wb + (size_t)(n0 + r)*KTOT + k0 + kgg*8, (char*)Bs + (size_t)s*16);
    }
    __syncthreads();
    #pragma unroll
    for (int ks = 0; ks < 2; ks++){
      int kq = ks*4 + (lane >> 4);
      short8v af[4], bf[4];
      #pragma unroll
      for (int t = 0; t < 4; t++){
        int ar = wr*64 + t*16 + (lane & 15);
        int as_ = ar*8 + (kq ^ (ar & 7));
        af[t] = *(const short8v*)((const char*)As + (size_t)as_*16);
        int br = wc*64 + t*16 + (lane & 15);
        int bs_ = br*8 + (kq ^ (br & 7));
        bf[t] = *(const short8v*)((const char*)Bs + (size_t)bs_*16);
      }
      #pragma unroll
      for (int i = 0; i < 4; i++)
        #pragma unroll
        for (int j = 0; j < 4; j++)
          acc[i][j] = __builtin_amdgcn_mfma_f32_16x16x32_bf16(af[i], bf[j], acc[i][j], 0, 0, 0);
    }
  }

  float* C = Cp + (size_t)kt*MKV*D_MODEL;
  #pragma unroll
  for (int i = 0; i < 4; i++){
    int mb = m0 + wr*64 + i*16 + ((lane >> 4) << 2);
    #pragma unroll
    for (int j = 0; j < 4; j++){
      int n = n0 + wc*64 + j*16 + (lane & 15);
      #pragma unroll
      for (int r = 0; r < 4; r++){
        int m = mb + r;
        if (m < MKV) C[(size_t)m*D_MODEL + n] = acc[i][j][r];
      }
    }
  }
}

// ---------------------------------------------------------------------------
// LN over y0+y1+y2+bias (sums the 3 split-K GEMM partials)
// ---------------------------------------------------------------------------
__global__ __launch_bounds__(256) void ln_rows3_kernel(
    const float* __restrict__ Y0, const float* __restrict__ Y1,
    const float* __restrict__ Y2, const float* __restrict__ bias,
    const float* __restrict__ lnw, const float* __restrict__ lnb,
    float* __restrict__ out)
{
  __shared__ float red[256], red2[256];
  int r = blockIdx.x, tid = threadIdx.x;
  const float* y0 = Y0 + (size_t)r*D_MODEL;
  const float* y1 = Y1 + (size_t)r*D_MODEL;
  const float* y2 = Y2 + (size_t)r*D_MODEL;
  float x0 = y0[tid      ] + y1[tid      ] + y2[tid      ] + bias[tid      ];
  float x1 = y0[tid + 256] + y1[tid + 256] + y2[tid + 256] + bias[tid + 256];
  float x2 = y0[tid + 512] + y1[tid + 512] + y2[tid + 512] + bias[tid + 512];
  red[tid] = x0 + x1 + x2; red2[tid] = x0*x0 + x1*x1 + x2*x2;
  __syncthreads();
  for (int st = 128; st > 0; st >>= 1){
    if (tid < st){ red[tid] += red[tid+st]; red2[tid] += red2[tid+st]; }
    __syncthreads();
  }
  float mean = red[0]*(1.f/768.f);
  float var  = red2[0]*(1.f/768.f) - mean*mean;
  float inv  = rsqrtf(var + LN_EPSF);
  float* orow = out + (size_t)r*D_MODEL;
  orow[tid      ] = (x0-mean)*inv*lnw[tid      ] + lnb[tid      ];
  orow[tid + 256] = (x1-mean)*inv*lnw[tid + 256] + lnb[tid + 256];
  orow[tid + 512] = (x2-mean)*inv*lnw[tid + 512] + lnb[tid + 512];
}

// ---------------------------------------------------------------------------
// Attention partials over a P-CHUNK (occupancy-oriented rewrite):
//   grid (16, 12, 4): z = half*2 + c;  chunk c covers p in [c*100, c?197:100)
//   A[p,d] stride 65 (R6-proven conflict-free), all-b32 LDS access.
//   outputs per (idx = ((r*12+h)*2+half)*8+q): mC,zC [c][idx], UC[c][idx][64]
// LDS ~= 31 KB -> 3 blocks/CU resident; 768 blocks -> 12 waves/CU.
// ---------------------------------------------------------------------------
__global__ __launch_bounds__(256) void rank_chunk_kernel(
    const float* __restrict__ kv_ln, const float* __restrict__ q_ln,
    const float* __restrict__ ppe,
    float* __restrict__ mC, float* __restrict__ zC, float* __restrict__ UC)
{
  __shared__ float A[CHMAX*65];    // 25.4 KB
  __shared__ float qs[NQR*64];     //  2 KB
  __shared__ float E[NQR*EROW];    //  3.25 KB
  int r = blockIdx.x, h = blockIdx.y;
  int half = blockIdx.z >> 1, c = blockIdx.z & 1;
  int p0 = c ? CH0 : 0;
  int np = c ? CH1 : CH0;
  int tid = threadIdx.x;

  for (int e = tid; e < NQR*64; e += 256){
    int q = e >> 6, d = e & 63;
    qs[e] = q_ln[q*D_MODEL + h*64 + d];
  }
  // stage A chunk: coalesced float4 global reads, b32 LDS writes (stride 65)
  for (int e = tid; e < np*16; e += 256){
    int p = e >> 4, dq = (e & 15) << 2;
    float4 a = *(const float4*)&kv_ln[((size_t)(r*PP + p0 + p))*D_MODEL + h*64 + dq];
    float4 b = *(const float4*)&ppe[((size_t)(half*PP + p0 + p))*D_MODEL + h*64 + dq];
    float* row = &A[p*65 + dq];
    row[0] = a.x + b.x; row[1] = a.y + b.y;
    row[2] = a.z + b.z; row[3] = a.w + b.w;
  }
  __syncthreads();

  int q = tid >> 5, sub = tid & 31;
  // ---- scores over chunk: s[q, p_local] ----
  float s[4];
  #pragma unroll
  for (int i = 0; i < 4; i++) s[i] = 0.f;
  for (int d = 0; d < 64; d++){
    float qv = qs[q*64 + d];
    #pragma unroll
    for (int i = 0; i < 4; i++){
      int p = sub + 32*i;
      int pc = p < np ? p : np-1;
      s[i] += qv * A[pc*65 + d];
    }
  }
  float mloc = -1e30f;
  #pragma unroll
  for (int i = 0; i < 4; i++){
    int p = sub + 32*i;
    s[i] = (p < np) ? s[i]*SCALEF : -1e30f;
    mloc = fmaxf(mloc, s[i]);
  }
  for (int off = 16; off >= 1; off >>= 1)
    mloc = fmaxf(mloc, __shfl_xor(mloc, off, 32));
  float zloc = 0.f;
  #pragma unroll
  for (int i = 0; i < 4; i++){
    int p = sub + 32*i;
    float e = __expf(s[i] - mloc);
    if (p < np){ E[q*EROW + p] = e; zloc += e; }
  }
  for (int off = 16; off >= 1; off >>= 1)
    zloc += __shfl_xor(zloc, off, 32);

  int idx = (((r*NHEADS + h)*2 + half)*NQR + q);
  if (sub == 0){
    mC[c*NIDX + idx] = mloc;
    zC[c*NIDX + idx] = zloc;
  }
  // E written/read by same 32-lane group -> no barrier needed

  // ---- U[q][d] partial over chunk ----
  float u0 = 0.f, u1 = 0.f;
  for (int p = 0; p < np; p++){
    float e = E[q*EROW + p];
    u0 += e * A[p*65 + sub];
    u1 += e * A[p*65 + sub + 32];
  }
  float* urow = UC + ((size_t)(c*NIDX + idx))*64;
  urow[sub]      = u0;
  urow[sub + 32] = u1;
}

// ---------------------------------------------------------------------------
// Merge the 2 chunk partials (online-softmax) + out_w projection.
// grid (16, 12, 2) = 384 blocks, 256 threads.
//   mm = max(m0,m1); a_c = exp(m_c-mm); z = a0 z0 + a1 z1 (-> m/z for combine)
//   U[q][d] = a0 U0 + a1 U1  (LDS)
//   P[r,h,q,n] = sum_d U[q][d] * ow[n][h*64+d]
// ---------------------------------------------------------------------------
__global__ __launch_bounds__(256) void merge_proj_kernel(
    const float* __restrict__ mC, const float* __restrict__ zC,
    const float* __restrict__ UC, const float* __restrict__ ow,
    float* __restrict__ m1O, float* __restrict__ z1O,
    float* __restrict__ m2O, float* __restrict__ z2O,
    float* __restrict__ p1, float* __restrict__ p2)
{
  __shared__ float Us[NQR*64];
  __shared__ float a0s[NQR], a1s[NQR];
  int r = blockIdx.x, h = blockIdx.y, half = blockIdx.z;
  int tid = threadIdx.x;
  int base = (((r*NHEADS + h)*2 + half)*NQR);

  if (tid < NQR){
    int q = tid;
    float m0 = mC[base + q],        m1v = mC[NIDX + base + q];
    float z0 = zC[base + q],        z1v = zC[NIDX + base + q];
    float mm = fmaxf(m0, m1v);
    float a0 = __expf(m0 - mm), a1 = __expf(m1v - mm);
    a0s[q] = a0; a1s[q] = a1;
    int oidx = (r*NHEADS + h)*NQR + q;
    if (half){ m2O[oidx] = mm; z2O[oidx] = a0*z0 + a1*z1v; }
    else     { m1O[oidx] = mm; z1O[oidx] = a0*z0 + a1*z1v; }
  }
  __syncthreads();
  for (int e = tid; e < NQR*64; e += 256){
    int q = e >> 6;
    Us[e] = a0s[q]*UC[((size_t)(base))*64 + e]
          + a1s[q]*UC[((size_t)(NIDX + base))*64 + e];
  }
  __syncthreads();

  // ---- projection: P[q][n] = sum_d Us[q][d] * ow[n][h*64+d] ----
  float acc[NQR][3];
  #pragma unroll
  for (int m = 0; m < NQR; m++){ acc[m][0]=0.f; acc[m][1]=0.f; acc[m][2]=0.f; }
  const float* owh = ow + h*64;
  for (int d4 = 0; d4 < 64; d4 += 4){
    float4 w0 = *(const float4*)&owh[(size_t)(tid      )*D_MODEL + d4];
    float4 w1 = *(const float4*)&owh[(size_t)(tid + 256)*D_MODEL + d4];
    float4 w2 = *(const float4*)&owh[(size_t)(tid + 512)*D_MODEL + d4];
    #pragma unroll
    for (int m = 0; m < NQR; m++){
      float4 u = *(const float4*)&Us[m*64 + d4];
      acc[m][0] += u.x*w0.x + u.y*w0.y + u.z*w0.z + u.w*w0.w;
      acc[m][1] += u.x*w1.x + u.y*w1.y + u.z*w1.z + u.w*w1.w;
      acc[m][2] += u.x*w2.x + u.y*w2.y + u.z*w2.z + u.w*w2.w;
    }
  }
  float* P = half ? p2 : p1;
  #pragma unroll
  for (int m = 0; m < NQR; m++){
    size_t obase = (((size_t)r*NHEADS + h)*NQR + m)*D_MODEL;
    #pragma unroll
    for (int j = 0; j < 3; j++)
      P[obase + tid + 256*j] = acc[m][j];
  }
}

// ---------------------------------------------------------------------------
// Final combine:
//   out[(i*16+j)*8+q, n] = sum_h c1[h]*P1[i,h,q,n] - c2[h]*P2[j,h,q,n] + out_b[n]
// ---------------------------------------------------------------------------
__global__ __launch_bounds__(256) void combine_out_kernel(
    const float* __restrict__ m1, const float* __restrict__ z1,
    const float* __restrict__ m2, const float* __restrict__ z2,
    const float* __restrict__ p1, const float* __restrict__ p2,
    const float* __restrict__ out_b, float* __restrict__ out)
{
  __shared__ float c1s[NHEADS], c2s[NHEADS];
  int pair = blockIdx.x, q = blockIdx.y, tid = threadIdx.x;
  int i = pair >> 4, j = pair & 15;
  if (tid < NHEADS){
    int h = tid;
    int ii = (i*NHEADS + h)*NQR + q;
    int jj = (j*NHEADS + h)*NQR + q;
    float mi = m1[ii], mj = m2[jj];
    float mm = fmaxf(mi, mj);
    float a1 = __expf(mi - mm), a2 = __expf(mj - mm);
    float rden = 1.f / (a1*z1[ii] + a2*z2[jj]);
    c1s[h] = a1*rden; c2s[h] = a2*rden;
  }
  __syncthreads();
  float* orow = out + ((size_t)(pair*NQR + q))*D_MODEL;
  for (int nn = tid; nn < D_MODEL; nn += 256){
    float acc = out_b[nn];
    #pragma unroll
    for (int h = 0; h < NHEADS; h++){
      acc += c1s[h]*p1[(((size_t)i*NHEADS + h)*NQR + q)*D_MODEL + nn]
           - c2s[h]*p2[(((size_t)j*NHEADS + h)*NQR + q)*D_MODEL + nn];
    }
    orow[nn] = acc;
  }
}

// ---------------------------------------------------------------------------
extern "C" void kernel_launch(void* const* d_in, const int* in_sizes, int n_in,
                              void* d_out, int out_size, void* d_ws, size_t ws_size,
                              hipStream_t stream)
{
  const float* q_x    = (const float*)d_in[0];
  const float* kv_x   = (const float*)d_in[1];
  const float* ppe    = (const float*)d_in[2];
  const float* q_w    = (const float*)d_in[3];
  const float* q_b    = (const float*)d_in[4];
  const float* kv_w   = (const float*)d_in[5];
  const float* kv_b   = (const float*)d_in[6];
  const float* out_w  = (const float*)d_in[7];
  const float* out_b  = (const float*)d_in[8];
  const float* lnq_w  = (const float*)d_in[9];
  const float* lnq_b  = (const float*)d_in[10];
  const float* lnkv_w = (const float*)d_in[11];
  const float* lnkv_b = (const float*)d_in[12];
  float* out = (float*)d_out;

  // workspace (f32 units). Aliasing by lifetime:
  //   Abuf (bf16, dead after gemm) <- later kv_ln
  //   Wbuf (bf16, dead after gemm) <- later mC/zC/UC + m/z for combine
  //   C0..C2 (gemm partials, dead after ln3) <- later p1,p2
  float* ws    = (float*)d_ws;
  float* q_y   = ws;                              //  6144
  float* q_ln  = q_y  + NQR*D_MODEL;              //  6144
  float* Abuf_f = q_ln + NQR*D_MODEL;             //  3,686,400 (3200*2304 bf16)
  float* Wbuf_f = Abuf_f + (size_t)MPAD*KTOT/2;   //    884,736 (768*2304 bf16)
  float* C0    = Wbuf_f + (size_t)D_MODEL*KTOT/2; //  3x 2,420,736
  float* C1    = C0 + (size_t)MKV*D_MODEL;
  float* C2    = C1 + (size_t)MKV*D_MODEL;

  __hip_bfloat16* Abuf = (__hip_bfloat16*)Abuf_f;
  __hip_bfloat16* Wbuf = (__hip_bfloat16*)Wbuf_f;

  float* kv_ln = Abuf_f;                          // alias (2,420,736 <= 3,686,400)
  // Wbuf region: mC(6144) zC(6144) UC(393,216) m1..z2(4x1536) = 411,648 ok
  float* mC    = Wbuf_f;
  float* zC    = mC + NCHUNK*NIDX;
  float* UC    = zC + NCHUNK*NIDX;
  float* m1    = UC + (size_t)NCHUNK*NIDX*64;
  float* z1    = m1 + BB*NHEADS*NQR;
  float* m2    = z1 + BB*NHEADS*NQR;
  float* z2    = m2 + BB*NHEADS*NQR;
  float* p1    = C0;                              // alias (2,359,296 <= 7,262,208)
  float* p2    = p1 + (size_t)BB*NHEADS*NQR*D_MODEL;

  qgemm_kernel<<<96, 256, 0, stream>>>(q_x, q_w, q_y);
  ln_rows_kernel<<<NQR, 256, 0, stream>>>(q_y, q_b, lnq_w, lnq_b, q_ln);

  pack_both_kernel<<<MPAD + D_MODEL, 192, 0, stream>>>(kv_x, kv_w, Abuf, Wbuf);

  gemm_mfma_kernel<<<dim3(MPAD/BM, D_MODEL/BN, KSPLIT), 256, 0, stream>>>(
      Abuf, Wbuf, C0);

  ln_rows3_kernel<<<MKV, 256, 0, stream>>>(C0, C1, C2, kv_b, lnkv_w, lnkv_b, kv_ln);

  rank_chunk_kernel<<<dim3(BB, NHEADS, 4), 256, 0, stream>>>(
      kv_ln, q_ln, ppe, mC, zC, UC);

  merge_proj_kernel<<<dim3(BB, NHEADS, 2), 256, 0, stream>>>(
      mC, zC, UC, out_w, m1, z1, m2, z2, p1, p2);

  combine_out_kernel<<<dim3(NPAIR, NQR), 256, 0, stream>>>(
      m1, z1, m2, z2, p1, p2, out_b, out);
}

// Round 9
// 175.389 us; speedup vs baseline: 1.0786x; 1.0177x over previous
//
#include <hip/hip_runtime.h>
#include <hip/hip_bf16.h>
#include <math.h>

#define D_MODEL 768
#define NHEADS  12
#define DHEAD   64
#define NQR     8     // query rows
#define BB      16    // batch (ranks)
#define PP      197   // tokens per rank
#define NPAIR   256   // BB*BB
#define MKV     (BB*PP)     // 3152
#define LN_EPSF 1e-5f
#define SCALEF  0.125f      // 64^-0.5

// split-bf16 K-extended GEMM params
#define KTOT  2304          // 3*768:  [a_hi|a_hi|a_lo] x [w_hi|w_lo|w_hi]
#define KSPLIT 3
#define KPER  (KTOT/KSPLIT) // 768
#define MPAD  3200          // 25*128
#define BM 128
#define BN 128
#define BK 64

#define CH0   100           // chunk 0: p in [0,100)
#define CH1   97            // chunk 1: p in [100,197)
#define CHMAX 100

typedef __attribute__((ext_vector_type(8))) short short8v;   // 8 bf16
typedef __attribute__((ext_vector_type(4))) float float4v;   // mfma acc

__device__ __forceinline__ void gload16(const void* g, void* l){
  __builtin_amdgcn_global_load_lds(
      (const __attribute__((address_space(1))) unsigned int*)g,
      (__attribute__((address_space(3))) unsigned int*)l, 16, 0, 0);
}

__device__ __forceinline__ float lane_bcast(float v, int src){
  return __int_as_float(__builtin_amdgcn_readlane(__float_as_int(v), src));
}

// ---------------------------------------------------------------------------
// prep: fused pack + q GEMM.
// blocks [0, MPAD)               : pack kv_x row -> Ab  [hi, hi, lo]
// blocks [MPAD, MPAD+768)        : pack kv_w row -> Wb  [hi, lo, hi]
// blocks [MPAD+768, MPAD+768+128): q GEMM, 6 cols/block x 32 lanes/col
//   (R5 lesson: columns use 32 coalesced lanes, never per-thread serial dots)
// ---------------------------------------------------------------------------
__global__ __launch_bounds__(192) void prep_kernel(
    const float* __restrict__ kvx, const float* __restrict__ kvw,
    __hip_bfloat16* __restrict__ Ab, __hip_bfloat16* __restrict__ Wb,
    const float* __restrict__ qx, const float* __restrict__ qw,
    float* __restrict__ qy)
{
  __shared__ float xs[NQR*D_MODEL];
  int b = blockIdx.x, t = threadIdx.x;
  if (b < MPAD + D_MODEL){
    const float* X; __hip_bfloat16* Y; int valid, mode, m;
    if (b < MPAD){ X = kvx; Y = Ab; valid = MKV;     mode = 0; m = b; }
    else         { X = kvw; Y = Wb; valid = D_MODEL; mode = 1; m = b - MPAD; }
    int k = t*4;
    float4 v = (m < valid) ? *(const float4*)&X[(size_t)m*D_MODEL + k]
                           : make_float4(0.f,0.f,0.f,0.f);
    float xsv[4] = {v.x, v.y, v.z, v.w};
    unsigned short hu[4], lu[4];
    #pragma unroll
    for (int i = 0; i < 4; i++){
      __hip_bfloat16 h = __float2bfloat16(xsv[i]);
      float hf = __bfloat162float(h);
      __hip_bfloat16 l = __float2bfloat16(xsv[i] - hf);
      hu[i] = *(unsigned short*)&h;
      lu[i] = *(unsigned short*)&l;
    }
    ushort4 hv = {hu[0], hu[1], hu[2], hu[3]};
    ushort4 lv = {lu[0], lu[1], lu[2], lu[3]};
    ushort4* row = (ushort4*)(Y + (size_t)m*KTOT);
    int s = k >> 2;
    if (mode == 0){ row[s] = hv; row[s+192] = hv; row[s+384] = lv; }
    else          { row[s] = hv; row[s+192] = lv; row[s+384] = hv; }
    return;
  }
  // ---- q GEMM: block covers 6 output cols, 32 lanes each ----
  int b2 = b - (MPAD + D_MODEL);
  for (int e = t*4; e < NQR*D_MODEL; e += 768)
    *(float4*)&xs[e] = *(const float4*)&qx[e];
  __syncthreads();
  int col = t >> 5, lane = t & 31;
  int c = b2*6 + col;
  const float* wr = qw + (size_t)c*D_MODEL;
  float acc[NQR] = {};
  for (int k = lane*4; k < D_MODEL; k += 128){
    float4 w4 = *(const float4*)&wr[k];
    #pragma unroll
    for (int q = 0; q < NQR; q++){
      float4 x4 = *(const float4*)&xs[q*D_MODEL + k];
      acc[q] += x4.x*w4.x + x4.y*w4.y + x4.z*w4.z + x4.w*w4.w;
    }
  }
  #pragma unroll
  for (int q = 0; q < NQR; q++){
    float a = acc[q];
    for (int off = 16; off >= 1; off >>= 1) a += __shfl_xor(a, off, 32);
    if (lane == 0) qy[q*D_MODEL + c] = a;
  }
}

// ---------------------------------------------------------------------------
// bf16 MFMA GEMM: C[kt][m][n] partial over K-split (kt = 0..2).  (unchanged)
// ---------------------------------------------------------------------------
__global__ __launch_bounds__(256) void gemm_mfma_kernel(
    const __hip_bfloat16* __restrict__ Ab, const __hip_bfloat16* __restrict__ Wb,
    float* __restrict__ Cp)
{
  __shared__ __hip_bfloat16 As[BM*BK];   // 16 KB
  __shared__ __hip_bfloat16 Bs[BN*BK];   // 16 KB
  int tid = threadIdx.x;
  int wave = tid >> 6, lane = tid & 63;
  int m0 = blockIdx.x*BM, n0 = blockIdx.y*BN, kt = blockIdx.z;
  int wr = wave >> 1, wc = wave & 1;

  float4v acc[4][4];
  #pragma unroll
  for (int i = 0; i < 4; i++)
    #pragma unroll
    for (int j = 0; j < 4; j++)
      acc[i][j] = (float4v){0.f, 0.f, 0.f, 0.f};

  int sbase = wave*256;
  for (int st = 0; st < KPER/BK; ++st){
    int k0 = kt*KPER + st*BK;
    __syncthreads();
    #pragma unroll
    for (int i = 0; i < 4; i++){
      int s  = sbase + i*64 + lane;
      int r  = s >> 3, kg = s & 7;
      int kgg = kg ^ (r & 7);
      gload16(Ab + (size_t)(m0 + r)*KTOT + k0 + kgg*8, (char*)As + (size_t)s*16);
      gload16(Wb + (size_t)(n0 + r)*KTOT + k0 + kgg*8, (char*)Bs + (size_t)s*16);
    }
    __syncthreads();
    #pragma unroll
    for (int ks = 0; ks < 2; ks++){
      int kq = ks*4 + (lane >> 4);
      short8v af[4], bf[4];
      #pragma unroll
      for (int t = 0; t < 4; t++){
        int ar = wr*64 + t*16 + (lane & 15);
        int as_ = ar*8 + (kq ^ (ar & 7));
        af[t] = *(const short8v*)((const char*)As + (size_t)as_*16);
        int br = wc*64 + t*16 + (lane & 15);
        int bs_ = br*8 + (kq ^ (br & 7));
        bf[t] = *(const short8v*)((const char*)Bs + (size_t)bs_*16);
      }
      #pragma unroll
      for (int i = 0; i < 4; i++)
        #pragma unroll
        for (int j = 0; j < 4; j++)
          acc[i][j] = __builtin_amdgcn_mfma_f32_16x16x32_bf16(af[i], bf[j], acc[i][j], 0, 0, 0);
    }
  }

  float* C = Cp + (size_t)kt*MKV*D_MODEL;
  #pragma unroll
  for (int i = 0; i < 4; i++){
    int mb = m0 + wr*64 + i*16 + ((lane >> 4) << 2);
    #pragma unroll
    for (int j = 0; j < 4; j++){
      int n = n0 + wc*64 + j*16 + (lane & 15);
      #pragma unroll
      for (int r = 0; r < 4; r++){
        int m = mb + r;
        if (m < MKV) C[(size_t)m*D_MODEL + n] = acc[i][j][r];
      }
    }
  }
}

// ---------------------------------------------------------------------------
// ln_all: blocks [0,MKV) = kv rows: LN(C0+C1+C2+kv_b) -> kv_ln
//         blocks [MKV, MKV+8) = q rows: LN(q_y+q_b)   -> q_ln
// ---------------------------------------------------------------------------
__global__ __launch_bounds__(256) void ln_all_kernel(
    const float* __restrict__ C0, const float* __restrict__ C1,
    const float* __restrict__ C2, const float* __restrict__ kv_b,
    const float* __restrict__ lnkv_w, const float* __restrict__ lnkv_b,
    float* __restrict__ kv_ln,
    const float* __restrict__ q_y, const float* __restrict__ q_b,
    const float* __restrict__ lnq_w, const float* __restrict__ lnq_b,
    float* __restrict__ q_ln)
{
  __shared__ float red[256], red2[256];
  int b = blockIdx.x, tid = threadIdx.x;
  const float *xa, *xb, *xc, *bias, *lw, *lb; float* outp; bool three;
  if (b < MKV){
    xa = C0 + (size_t)b*D_MODEL; xb = C1 + (size_t)b*D_MODEL;
    xc = C2 + (size_t)b*D_MODEL;
    bias = kv_b; lw = lnkv_w; lb = lnkv_b;
    outp = kv_ln + (size_t)b*D_MODEL; three = true;
  } else {
    int r = b - MKV;
    xa = q_y + (size_t)r*D_MODEL; xb = xa; xc = xa;
    bias = q_b; lw = lnq_w; lb = lnq_b;
    outp = q_ln + (size_t)r*D_MODEL; three = false;
  }
  float x0 = xa[tid      ] + (three ? xb[tid      ] + xc[tid      ] : 0.f) + bias[tid      ];
  float x1 = xa[tid + 256] + (three ? xb[tid + 256] + xc[tid + 256] : 0.f) + bias[tid + 256];
  float x2 = xa[tid + 512] + (three ? xb[tid + 512] + xc[tid + 512] : 0.f) + bias[tid + 512];
  red[tid] = x0 + x1 + x2; red2[tid] = x0*x0 + x1*x1 + x2*x2;
  __syncthreads();
  for (int st = 128; st > 0; st >>= 1){
    if (tid < st){ red[tid] += red[tid+st]; red2[tid] += red2[tid+st]; }
    __syncthreads();
  }
  float mean = red[0]*(1.f/768.f);
  float var  = red2[0]*(1.f/768.f) - mean*mean;
  float inv  = rsqrtf(var + LN_EPSF);
  outp[tid      ] = (x0-mean)*inv*lw[tid      ] + lb[tid      ];
  outp[tid + 256] = (x1-mean)*inv*lw[tid + 256] + lb[tid + 256];
  outp[tid + 512] = (x2-mean)*inv*lw[tid + 512] + lb[tid + 512];
}

// ---------------------------------------------------------------------------
// rank_proj: per (r, h, half) block (grid 16x12x2, 256 thr = 4 waves).
// Max-free softmax (|s| ~ O(6), raw exp safe): z = sum exp(s), U = sum exp*A.
// Two sequential p-chunks reuse one 100-row A buffer (26 KB -> 5 blocks/CU).
// Wave w owns q rows {2w, 2w+1}: q read from GLOBAL (L1-hot, vmem pipe),
// E kept in registers, U-loop broadcasts e via v_readlane (VALU not LDS).
// Then projection: P[q][n] = sum_d U[q][d] * ow[n][h*64+d].
// ---------------------------------------------------------------------------
__global__ __launch_bounds__(256) void rank_proj_kernel(
    const float* __restrict__ kv_ln, const float* __restrict__ q_ln,
    const float* __restrict__ ppe, const float* __restrict__ ow,
    float* __restrict__ z1O, float* __restrict__ z2O,
    float* __restrict__ p1, float* __restrict__ p2)
{
  __shared__ float A[CHMAX*65];    // 26 KB, stride 65 (conflict-free)
  __shared__ float Us[NQR*64];     //  2 KB
  int r = blockIdx.x, h = blockIdx.y, half = blockIdx.z;
  int tid = threadIdx.x;
  int wave = tid >> 6, lane = tid & 63;
  int qa = 2*wave, qb = qa + 1;
  const float* qrowA = q_ln + (size_t)qa*D_MODEL + h*64;
  const float* qrowB = q_ln + (size_t)qb*D_MODEL + h*64;

  float ua = 0.f, ub = 0.f;        // U[qa][lane], U[qb][lane]
  float za = 0.f, zb = 0.f;        // z partial per lane

  for (int c = 0; c < 2; c++){
    int p0 = c ? CH0 : 0;
    int np = c ? CH1 : CH0;
    __syncthreads();               // prior chunk's A reads complete
    for (int e = tid; e < np*16; e += 256){
      int p = e >> 4, dq = (e & 15) << 2;
      float4 a = *(const float4*)&kv_ln[((size_t)(r*PP + p0 + p))*D_MODEL + h*64 + dq];
      float4 b = *(const float4*)&ppe[((size_t)(half*PP + p0 + p))*D_MODEL + h*64 + dq];
      float* rw = &A[p*65 + dq];
      rw[0] = a.x + b.x; rw[1] = a.y + b.y;
      rw[2] = a.z + b.z; rw[3] = a.w + b.w;
    }
    __syncthreads();

    // scores: slot0 p=lane (<97<=np always valid), slot1 p=lane+64
    int p1v = lane + 64;
    bool v1 = p1v < np;
    int p1c = v1 ? p1v : 0;
    float s0a = 0.f, s0b = 0.f, s1a = 0.f, s1b = 0.f;
    for (int d = 0; d < 64; d++){
      float qva = qrowA[d];
      float qvb = qrowB[d];
      float a0 = A[lane*65 + d];
      float a1 = A[p1c*65 + d];
      s0a += qva*a0; s1a += qva*a1;
      s0b += qvb*a0; s1b += qvb*a1;
    }
    float e0a = __expf(s0a*SCALEF);
    float e0b = __expf(s0b*SCALEF);
    float e1a = v1 ? __expf(s1a*SCALEF) : 0.f;
    float e1b = v1 ? __expf(s1b*SCALEF) : 0.f;
    za += e0a + e1a;
    zb += e0b + e1b;

    // U accumulation: broadcast e across lanes (VALU readlane, LDS only for A)
    for (int p = 0; p < 64; p++){
      float av = A[p*65 + lane];
      ua += lane_bcast(e0a, p) * av;
      ub += lane_bcast(e0b, p) * av;
    }
    for (int p = 64; p < np; p++){
      float av = A[p*65 + lane];
      ua += lane_bcast(e1a, p - 64) * av;
      ub += lane_bcast(e1b, p - 64) * av;
    }
  }

  // z: full-wave sum
  for (int off = 32; off >= 1; off >>= 1){
    za += __shfl_xor(za, off);
    zb += __shfl_xor(zb, off);
  }
  float* zO = half ? z2O : z1O;
  if (lane == 0){
    zO[(r*NHEADS + h)*NQR + qa] = za;
    zO[(r*NHEADS + h)*NQR + qb] = zb;
  }
  Us[qa*64 + lane] = ua;
  Us[qb*64 + lane] = ub;
  __syncthreads();

  // projection: P[q][n] = sum_d Us[q][d] * ow[n][h*64+d]
  float acc[NQR][3];
  #pragma unroll
  for (int m = 0; m < NQR; m++){ acc[m][0]=0.f; acc[m][1]=0.f; acc[m][2]=0.f; }
  const float* owh = ow + h*64;
  for (int d4 = 0; d4 < 64; d4 += 4){
    float4 w0 = *(const float4*)&owh[(size_t)(tid      )*D_MODEL + d4];
    float4 w1 = *(const float4*)&owh[(size_t)(tid + 256)*D_MODEL + d4];
    float4 w2 = *(const float4*)&owh[(size_t)(tid + 512)*D_MODEL + d4];
    #pragma unroll
    for (int m = 0; m < NQR; m++){
      float4 u = *(const float4*)&Us[m*64 + d4];
      acc[m][0] += u.x*w0.x + u.y*w0.y + u.z*w0.z + u.w*w0.w;
      acc[m][1] += u.x*w1.x + u.y*w1.y + u.z*w1.z + u.w*w1.w;
      acc[m][2] += u.x*w2.x + u.y*w2.y + u.z*w2.z + u.w*w2.w;
    }
  }
  float* P = half ? p2 : p1;
  #pragma unroll
  for (int m = 0; m < NQR; m++){
    size_t obase = (((size_t)r*NHEADS + h)*NQR + m)*D_MODEL;
    #pragma unroll
    for (int j = 0; j < 3; j++)
      P[obase + tid + 256*j] = acc[m][j];
  }
}

// ---------------------------------------------------------------------------
// Final combine (max-free):
//   out[(i*16+j)*8+q, n] = out_b[n] + sum_h (P1[i,h,q,n]-P2[j,h,q,n])/(z1+z2)
// ---------------------------------------------------------------------------
__global__ __launch_bounds__(256) void combine_out_kernel(
    const float* __restrict__ z1, const float* __restrict__ z2,
    const float* __restrict__ p1, const float* __restrict__ p2,
    const float* __restrict__ out_b, float* __restrict__ out)
{
  __shared__ float cs[NHEADS];
  int pair = blockIdx.x, q = blockIdx.y, tid = threadIdx.x;
  int i = pair >> 4, j = pair & 15;
  if (tid < NHEADS){
    int h = tid;
    int ii = (i*NHEADS + h)*NQR + q;
    int jj = (j*NHEADS + h)*NQR + q;
    cs[h] = 1.f / (z1[ii] + z2[jj]);
  }
  __syncthreads();
  float* orow = out + ((size_t)(pair*NQR + q))*D_MODEL;
  for (int nn = tid; nn < D_MODEL; nn += 256){
    float acc = out_b[nn];
    #pragma unroll
    for (int h = 0; h < NHEADS; h++){
      acc += cs[h]*(p1[(((size_t)i*NHEADS + h)*NQR + q)*D_MODEL + nn]
                  - p2[(((size_t)j*NHEADS + h)*NQR + q)*D_MODEL + nn]);
    }
    orow[nn] = acc;
  }
}

// ---------------------------------------------------------------------------
extern "C" void kernel_launch(void* const* d_in, const int* in_sizes, int n_in,
                              void* d_out, int out_size, void* d_ws, size_t ws_size,
                              hipStream_t stream)
{
  const float* q_x    = (const float*)d_in[0];
  const float* kv_x   = (const float*)d_in[1];
  const float* ppe    = (const float*)d_in[2];
  const float* q_w    = (const float*)d_in[3];
  const float* q_b    = (const float*)d_in[4];
  const float* kv_w   = (const float*)d_in[5];
  const float* kv_b   = (const float*)d_in[6];
  const float* out_w  = (const float*)d_in[7];
  const float* out_b  = (const float*)d_in[8];
  const float* lnq_w  = (const float*)d_in[9];
  const float* lnq_b  = (const float*)d_in[10];
  const float* lnkv_w = (const float*)d_in[11];
  const float* lnkv_b = (const float*)d_in[12];
  float* out = (float*)d_out;

  // workspace (f32 units). Aliasing by lifetime:
  //   Abuf (bf16, dead after gemm) <- later kv_ln
  //   Wbuf (bf16, dead after gemm) <- later z1,z2
  //   C0..C2 (gemm partials, dead after ln_all) <- later p1,p2
  float* ws    = (float*)d_ws;
  float* q_y   = ws;                              //  6144
  float* q_ln  = q_y  + NQR*D_MODEL;              //  6144
  float* Abuf_f = q_ln + NQR*D_MODEL;             //  3,686,400 (3200*2304 bf16)
  float* Wbuf_f = Abuf_f + (size_t)MPAD*KTOT/2;   //    884,736 (768*2304 bf16)
  float* C0    = Wbuf_f + (size_t)D_MODEL*KTOT/2; //  3x 2,420,736
  float* C1    = C0 + (size_t)MKV*D_MODEL;
  float* C2    = C1 + (size_t)MKV*D_MODEL;

  __hip_bfloat16* Abuf = (__hip_bfloat16*)Abuf_f;
  __hip_bfloat16* Wbuf = (__hip_bfloat16*)Wbuf_f;

  float* kv_ln = Abuf_f;                          // alias
  float* z1    = Wbuf_f;                          // alias
  float* z2    = z1 + BB*NHEADS*NQR;
  float* p1    = C0;                              // alias
  float* p2    = p1 + (size_t)BB*NHEADS*NQR*D_MODEL;

  prep_kernel<<<MPAD + D_MODEL + 128, 192, 0, stream>>>(
      kv_x, kv_w, Abuf, Wbuf, q_x, q_w, q_y);

  gemm_mfma_kernel<<<dim3(MPAD/BM, D_MODEL/BN, KSPLIT), 256, 0, stream>>>(
      Abuf, Wbuf, C0);

  ln_all_kernel<<<MKV + NQR, 256, 0, stream>>>(
      C0, C1, C2, kv_b, lnkv_w, lnkv_b, kv_ln,
      q_y, q_b, lnq_w, lnq_b, q_ln);

  rank_proj_kernel<<<dim3(BB, NHEADS, 2), 256, 0, stream>>>(
      kv_ln, q_ln, ppe, out_w, z1, z2, p1, p2);

  combine_out_kernel<<<dim3(NPAIR, NQR), 256, 0, stream>>>(
      z1, z2, p1, p2, out_b, out);
}

// Round 10
// 172.965 us; speedup vs baseline: 1.0938x; 1.0140x over previous
//
#include <hip/hip_runtime.h>
#include <hip/hip_bf16.h>
#include <math.h>

#define D_MODEL 768
#define NHEADS  12
#define DHEAD   64
#define NQR     8     // query rows
#define BB      16    // batch (ranks)
#define PP      197   // tokens per rank
#define NPAIR   256   // BB*BB
#define MKV     (BB*PP)     // 3152
#define LN_EPSF 1e-5f
#define SCALEF  0.125f      // 64^-0.5

// split-bf16 K-extended GEMM params
#define KTOT  2304          // 3*768:  [a_hi|a_hi|a_lo] x [w_hi|w_lo|w_hi]
#define KSPLIT 3
#define KPER  (KTOT/KSPLIT) // 768
#define MPAD  3200          // 25*128
#define BM 128
#define BN 128
#define BK 64

#define CH0   100           // chunk 0: p in [0,100)
#define CH1   97            // chunk 1: p in [100,197)
#define CHMAX 100

typedef __attribute__((ext_vector_type(8))) short short8v;   // 8 bf16
typedef __attribute__((ext_vector_type(4))) float float4v;   // mfma acc

__device__ __forceinline__ void gload16(const void* g, void* l){
  __builtin_amdgcn_global_load_lds(
      (const __attribute__((address_space(1))) unsigned int*)g,
      (__attribute__((address_space(3))) unsigned int*)l, 16, 0, 0);
}

__device__ __forceinline__ float lane_bcast(float v, int src){
  return __int_as_float(__builtin_amdgcn_readlane(__float_as_int(v), src));
}

// ---------------------------------------------------------------------------
// prep: fused pack + q GEMM.  (unchanged from R9)
// ---------------------------------------------------------------------------
__global__ __launch_bounds__(192) void prep_kernel(
    const float* __restrict__ kvx, const float* __restrict__ kvw,
    __hip_bfloat16* __restrict__ Ab, __hip_bfloat16* __restrict__ Wb,
    const float* __restrict__ qx, const float* __restrict__ qw,
    float* __restrict__ qy)
{
  __shared__ float xs[NQR*D_MODEL];
  int b = blockIdx.x, t = threadIdx.x;
  if (b < MPAD + D_MODEL){
    const float* X; __hip_bfloat16* Y; int valid, mode, m;
    if (b < MPAD){ X = kvx; Y = Ab; valid = MKV;     mode = 0; m = b; }
    else         { X = kvw; Y = Wb; valid = D_MODEL; mode = 1; m = b - MPAD; }
    int k = t*4;
    float4 v = (m < valid) ? *(const float4*)&X[(size_t)m*D_MODEL + k]
                           : make_float4(0.f,0.f,0.f,0.f);
    float xsv[4] = {v.x, v.y, v.z, v.w};
    unsigned short hu[4], lu[4];
    #pragma unroll
    for (int i = 0; i < 4; i++){
      __hip_bfloat16 h = __float2bfloat16(xsv[i]);
      float hf = __bfloat162float(h);
      __hip_bfloat16 l = __float2bfloat16(xsv[i] - hf);
      hu[i] = *(unsigned short*)&h;
      lu[i] = *(unsigned short*)&l;
    }
    ushort4 hv = {hu[0], hu[1], hu[2], hu[3]};
    ushort4 lv = {lu[0], lu[1], lu[2], lu[3]};
    ushort4* row = (ushort4*)(Y + (size_t)m*KTOT);
    int s = k >> 2;
    if (mode == 0){ row[s] = hv; row[s+192] = hv; row[s+384] = lv; }
    else          { row[s] = hv; row[s+192] = lv; row[s+384] = hv; }
    return;
  }
  // ---- q GEMM: block covers 6 output cols, 32 lanes each ----
  int b2 = b - (MPAD + D_MODEL);
  for (int e = t*4; e < NQR*D_MODEL; e += 768)
    *(float4*)&xs[e] = *(const float4*)&qx[e];
  __syncthreads();
  int col = t >> 5, lane = t & 31;
  int c = b2*6 + col;
  const float* wr = qw + (size_t)c*D_MODEL;
  float acc[NQR] = {};
  for (int k = lane*4; k < D_MODEL; k += 128){
    float4 w4 = *(const float4*)&wr[k];
    #pragma unroll
    for (int q = 0; q < NQR; q++){
      float4 x4 = *(const float4*)&xs[q*D_MODEL + k];
      acc[q] += x4.x*w4.x + x4.y*w4.y + x4.z*w4.z + x4.w*w4.w;
    }
  }
  #pragma unroll
  for (int q = 0; q < NQR; q++){
    float a = acc[q];
    for (int off = 16; off >= 1; off >>= 1) a += __shfl_xor(a, off, 32);
    if (lane == 0) qy[q*D_MODEL + c] = a;
  }
}

// ---------------------------------------------------------------------------
// bf16 MFMA GEMM: C[kt][m][n] partial over K-split (kt = 0..2).  (unchanged)
// ---------------------------------------------------------------------------
__global__ __launch_bounds__(256) void gemm_mfma_kernel(
    const __hip_bfloat16* __restrict__ Ab, const __hip_bfloat16* __restrict__ Wb,
    float* __restrict__ Cp)
{
  __shared__ __hip_bfloat16 As[BM*BK];   // 16 KB
  __shared__ __hip_bfloat16 Bs[BN*BK];   // 16 KB
  int tid = threadIdx.x;
  int wave = tid >> 6, lane = tid & 63;
  int m0 = blockIdx.x*BM, n0 = blockIdx.y*BN, kt = blockIdx.z;
  int wr = wave >> 1, wc = wave & 1;

  float4v acc[4][4];
  #pragma unroll
  for (int i = 0; i < 4; i++)
    #pragma unroll
    for (int j = 0; j < 4; j++)
      acc[i][j] = (float4v){0.f, 0.f, 0.f, 0.f};

  int sbase = wave*256;
  for (int st = 0; st < KPER/BK; ++st){
    int k0 = kt*KPER + st*BK;
    __syncthreads();
    #pragma unroll
    for (int i = 0; i < 4; i++){
      int s  = sbase + i*64 + lane;
      int r  = s >> 3, kg = s & 7;
      int kgg = kg ^ (r & 7);
      gload16(Ab + (size_t)(m0 + r)*KTOT + k0 + kgg*8, (char*)As + (size_t)s*16);
      gload16(Wb + (size_t)(n0 + r)*KTOT + k0 + kgg*8, (char*)Bs + (size_t)s*16);
    }
    __syncthreads();
    #pragma unroll
    for (int ks = 0; ks < 2; ks++){
      int kq = ks*4 + (lane >> 4);
      short8v af[4], bf[4];
      #pragma unroll
      for (int t = 0; t < 4; t++){
        int ar = wr*64 + t*16 + (lane & 15);
        int as_ = ar*8 + (kq ^ (ar & 7));
        af[t] = *(const short8v*)((const char*)As + (size_t)as_*16);
        int br = wc*64 + t*16 + (lane & 15);
        int bs_ = br*8 + (kq ^ (br & 7));
        bf[t] = *(const short8v*)((const char*)Bs + (size_t)bs_*16);
      }
      #pragma unroll
      for (int i = 0; i < 4; i++)
        #pragma unroll
        for (int j = 0; j < 4; j++)
          acc[i][j] = __builtin_amdgcn_mfma_f32_16x16x32_bf16(af[i], bf[j], acc[i][j], 0, 0, 0);
    }
  }

  float* C = Cp + (size_t)kt*MKV*D_MODEL;
  #pragma unroll
  for (int i = 0; i < 4; i++){
    int mb = m0 + wr*64 + i*16 + ((lane >> 4) << 2);
    #pragma unroll
    for (int j = 0; j < 4; j++){
      int n = n0 + wc*64 + j*16 + (lane & 15);
      #pragma unroll
      for (int r = 0; r < 4; r++){
        int m = mb + r;
        if (m < MKV) C[(size_t)m*D_MODEL + n] = acc[i][j][r];
      }
    }
  }
}

// ---------------------------------------------------------------------------
// ln_all: blocks [0,MKV) = kv rows, [MKV,MKV+8) = q rows.  (unchanged)
// ---------------------------------------------------------------------------
__global__ __launch_bounds__(256) void ln_all_kernel(
    const float* __restrict__ C0, const float* __restrict__ C1,
    const float* __restrict__ C2, const float* __restrict__ kv_b,
    const float* __restrict__ lnkv_w, const float* __restrict__ lnkv_b,
    float* __restrict__ kv_ln,
    const float* __restrict__ q_y, const float* __restrict__ q_b,
    const float* __restrict__ lnq_w, const float* __restrict__ lnq_b,
    float* __restrict__ q_ln)
{
  __shared__ float red[256], red2[256];
  int b = blockIdx.x, tid = threadIdx.x;
  const float *xa, *xb, *xc, *bias, *lw, *lb; float* outp; bool three;
  if (b < MKV){
    xa = C0 + (size_t)b*D_MODEL; xb = C1 + (size_t)b*D_MODEL;
    xc = C2 + (size_t)b*D_MODEL;
    bias = kv_b; lw = lnkv_w; lb = lnkv_b;
    outp = kv_ln + (size_t)b*D_MODEL; three = true;
  } else {
    int r = b - MKV;
    xa = q_y + (size_t)r*D_MODEL; xb = xa; xc = xa;
    bias = q_b; lw = lnq_w; lb = lnq_b;
    outp = q_ln + (size_t)r*D_MODEL; three = false;
  }
  float x0 = xa[tid      ] + (three ? xb[tid      ] + xc[tid      ] : 0.f) + bias[tid      ];
  float x1 = xa[tid + 256] + (three ? xb[tid + 256] + xc[tid + 256] : 0.f) + bias[tid + 256];
  float x2 = xa[tid + 512] + (three ? xb[tid + 512] + xc[tid + 512] : 0.f) + bias[tid + 512];
  red[tid] = x0 + x1 + x2; red2[tid] = x0*x0 + x1*x1 + x2*x2;
  __syncthreads();
  for (int st = 128; st > 0; st >>= 1){
    if (tid < st){ red[tid] += red[tid+st]; red2[tid] += red2[tid+st]; }
    __syncthreads();
  }
  float mean = red[0]*(1.f/768.f);
  float var  = red2[0]*(1.f/768.f) - mean*mean;
  float inv  = rsqrtf(var + LN_EPSF);
  outp[tid      ] = (x0-mean)*inv*lw[tid      ] + lb[tid      ];
  outp[tid + 256] = (x1-mean)*inv*lw[tid + 256] + lb[tid + 256];
  outp[tid + 512] = (x2-mean)*inv*lw[tid + 512] + lb[tid + 512];
}

// ---------------------------------------------------------------------------
// rank_proj: per (r, h, half) block.  (unchanged from R9)
// ---------------------------------------------------------------------------
__global__ __launch_bounds__(256) void rank_proj_kernel(
    const float* __restrict__ kv_ln, const float* __restrict__ q_ln,
    const float* __restrict__ ppe, const float* __restrict__ ow,
    float* __restrict__ z1O, float* __restrict__ z2O,
    float* __restrict__ p1, float* __restrict__ p2)
{
  __shared__ float A[CHMAX*65];    // 26 KB, stride 65 (conflict-free)
  __shared__ float Us[NQR*64];     //  2 KB
  int r = blockIdx.x, h = blockIdx.y, half = blockIdx.z;
  int tid = threadIdx.x;
  int wave = tid >> 6, lane = tid & 63;
  int qa = 2*wave, qb = qa + 1;
  const float* qrowA = q_ln + (size_t)qa*D_MODEL + h*64;
  const float* qrowB = q_ln + (size_t)qb*D_MODEL + h*64;

  float ua = 0.f, ub = 0.f;
  float za = 0.f, zb = 0.f;

  for (int c = 0; c < 2; c++){
    int p0 = c ? CH0 : 0;
    int np = c ? CH1 : CH0;
    __syncthreads();
    for (int e = tid; e < np*16; e += 256){
      int p = e >> 4, dq = (e & 15) << 2;
      float4 a = *(const float4*)&kv_ln[((size_t)(r*PP + p0 + p))*D_MODEL + h*64 + dq];
      float4 b = *(const float4*)&ppe[((size_t)(half*PP + p0 + p))*D_MODEL + h*64 + dq];
      float* rw = &A[p*65 + dq];
      rw[0] = a.x + b.x; rw[1] = a.y + b.y;
      rw[2] = a.z + b.z; rw[3] = a.w + b.w;
    }
    __syncthreads();

    int p1v = lane + 64;
    bool v1 = p1v < np;
    int p1c = v1 ? p1v : 0;
    float s0a = 0.f, s0b = 0.f, s1a = 0.f, s1b = 0.f;
    for (int d = 0; d < 64; d++){
      float qva = qrowA[d];
      float qvb = qrowB[d];
      float a0 = A[lane*65 + d];
      float a1 = A[p1c*65 + d];
      s0a += qva*a0; s1a += qva*a1;
      s0b += qvb*a0; s1b += qvb*a1;
    }
    float e0a = __expf(s0a*SCALEF);
    float e0b = __expf(s0b*SCALEF);
    float e1a = v1 ? __expf(s1a*SCALEF) : 0.f;
    float e1b = v1 ? __expf(s1b*SCALEF) : 0.f;
    za += e0a + e1a;
    zb += e0b + e1b;

    for (int p = 0; p < 64; p++){
      float av = A[p*65 + lane];
      ua += lane_bcast(e0a, p) * av;
      ub += lane_bcast(e0b, p) * av;
    }
    for (int p = 64; p < np; p++){
      float av = A[p*65 + lane];
      ua += lane_bcast(e1a, p - 64) * av;
      ub += lane_bcast(e1b, p - 64) * av;
    }
  }

  for (int off = 32; off >= 1; off >>= 1){
    za += __shfl_xor(za, off);
    zb += __shfl_xor(zb, off);
  }
  float* zO = half ? z2O : z1O;
  if (lane == 0){
    zO[(r*NHEADS + h)*NQR + qa] = za;
    zO[(r*NHEADS + h)*NQR + qb] = zb;
  }
  Us[qa*64 + lane] = ua;
  Us[qb*64 + lane] = ub;
  __syncthreads();

  float acc[NQR][3];
  #pragma unroll
  for (int m = 0; m < NQR; m++){ acc[m][0]=0.f; acc[m][1]=0.f; acc[m][2]=0.f; }
  const float* owh = ow + h*64;
  for (int d4 = 0; d4 < 64; d4 += 4){
    float4 w0 = *(const float4*)&owh[(size_t)(tid      )*D_MODEL + d4];
    float4 w1 = *(const float4*)&owh[(size_t)(tid + 256)*D_MODEL + d4];
    float4 w2 = *(const float4*)&owh[(size_t)(tid + 512)*D_MODEL + d4];
    #pragma unroll
    for (int m = 0; m < NQR; m++){
      float4 u = *(const float4*)&Us[m*64 + d4];
      acc[m][0] += u.x*w0.x + u.y*w0.y + u.z*w0.z + u.w*w0.w;
      acc[m][1] += u.x*w1.x + u.y*w1.y + u.z*w1.z + u.w*w1.w;
      acc[m][2] += u.x*w2.x + u.y*w2.y + u.z*w2.z + u.w*w2.w;
    }
  }
  float* P = half ? p2 : p1;
  #pragma unroll
  for (int m = 0; m < NQR; m++){
    size_t obase = (((size_t)r*NHEADS + h)*NQR + m)*D_MODEL;
    #pragma unroll
    for (int j = 0; j < 3; j++)
      P[obase + tid + 256*j] = acc[m][j];
  }
}

// ---------------------------------------------------------------------------
// Final combine (rewritten for traffic + vectorization):
// grid (i=16, q=8, jq=4) = 512 blocks, 192 threads; each block does 4 j's.
// p1[i,h,q,:] float4 loaded once per 4 outputs (traffic 147 -> ~94 MB).
//   out[(i*16+j)*8+q, n] = out_b[n] + sum_h (P1[i,h,q,n]-P2[j,h,q,n])/(z1+z2)
// ---------------------------------------------------------------------------
__global__ __launch_bounds__(192) void combine_out_kernel(
    const float* __restrict__ z1, const float* __restrict__ z2,
    const float* __restrict__ p1, const float* __restrict__ p2,
    const float* __restrict__ out_b, float* __restrict__ out)
{
  __shared__ float cs[4][NHEADS];
  int i = blockIdx.x, q = blockIdx.y, jq = blockIdx.z;
  int j0 = jq*4;
  int tid = threadIdx.x;
  if (tid < 4*NHEADS){
    int j = tid / NHEADS, h = tid % NHEADS;
    int ii = (i*NHEADS + h)*NQR + q;
    int jj = ((j0 + j)*NHEADS + h)*NQR + q;
    cs[j][h] = 1.f / (z1[ii] + z2[jj]);
  }
  __syncthreads();

  int n4 = tid*4;                        // 192 threads cover 768 cols
  float4 bv = *(const float4*)&out_b[n4];
  float4 acc[4];
  #pragma unroll
  for (int j = 0; j < 4; j++) acc[j] = bv;

  #pragma unroll
  for (int h = 0; h < NHEADS; h++){
    float4 a = *(const float4*)&p1[(((size_t)i*NHEADS + h)*NQR + q)*D_MODEL + n4];
    #pragma unroll
    for (int j = 0; j < 4; j++){
      float4 b = *(const float4*)&p2[(((size_t)(j0+j)*NHEADS + h)*NQR + q)*D_MODEL + n4];
      float c = cs[j][h];
      acc[j].x += c*(a.x - b.x);
      acc[j].y += c*(a.y - b.y);
      acc[j].z += c*(a.z - b.z);
      acc[j].w += c*(a.w - b.w);
    }
  }
  #pragma unroll
  for (int j = 0; j < 4; j++){
    int pair = i*BB + j0 + j;
    *(float4*)&out[((size_t)(pair*NQR + q))*D_MODEL + n4] = acc[j];
  }
}

// ---------------------------------------------------------------------------
extern "C" void kernel_launch(void* const* d_in, const int* in_sizes, int n_in,
                              void* d_out, int out_size, void* d_ws, size_t ws_size,
                              hipStream_t stream)
{
  const float* q_x    = (const float*)d_in[0];
  const float* kv_x   = (const float*)d_in[1];
  const float* ppe    = (const float*)d_in[2];
  const float* q_w    = (const float*)d_in[3];
  const float* q_b    = (const float*)d_in[4];
  const float* kv_w   = (const float*)d_in[5];
  const float* kv_b   = (const float*)d_in[6];
  const float* out_w  = (const float*)d_in[7];
  const float* out_b  = (const float*)d_in[8];
  const float* lnq_w  = (const float*)d_in[9];
  const float* lnq_b  = (const float*)d_in[10];
  const float* lnkv_w = (const float*)d_in[11];
  const float* lnkv_b = (const float*)d_in[12];
  float* out = (float*)d_out;

  float* ws    = (float*)d_ws;
  float* q_y   = ws;                              //  6144
  float* q_ln  = q_y  + NQR*D_MODEL;              //  6144
  float* Abuf_f = q_ln + NQR*D_MODEL;             //  3,686,400 (3200*2304 bf16)
  float* Wbuf_f = Abuf_f + (size_t)MPAD*KTOT/2;   //    884,736 (768*2304 bf16)
  float* C0    = Wbuf_f + (size_t)D_MODEL*KTOT/2; //  3x 2,420,736
  float* C1    = C0 + (size_t)MKV*D_MODEL;
  float* C2    = C1 + (size_t)MKV*D_MODEL;

  __hip_bfloat16* Abuf = (__hip_bfloat16*)Abuf_f;
  __hip_bfloat16* Wbuf = (__hip_bfloat16*)Wbuf_f;

  float* kv_ln = Abuf_f;                          // alias
  float* z1    = Wbuf_f;                          // alias
  float* z2    = z1 + BB*NHEADS*NQR;
  float* p1    = C0;                              // alias
  float* p2    = p1 + (size_t)BB*NHEADS*NQR*D_MODEL;

  prep_kernel<<<MPAD + D_MODEL + 128, 192, 0, stream>>>(
      kv_x, kv_w, Abuf, Wbuf, q_x, q_w, q_y);

  gemm_mfma_kernel<<<dim3(MPAD/BM, D_MODEL/BN, KSPLIT), 256, 0, stream>>>(
      Abuf, Wbuf, C0);

  ln_all_kernel<<<MKV + NQR, 256, 0, stream>>>(
      C0, C1, C2, kv_b, lnkv_w, lnkv_b, kv_ln,
      q_y, q_b, lnq_w, lnq_b, q_ln);

  rank_proj_kernel<<<dim3(BB, NHEADS, 2), 256, 0, stream>>>(
      kv_ln, q_ln, ppe, out_w, z1, z2, p1, p2);

  combine_out_kernel<<<dim3(BB, NQR, 4), 192, 0, stream>>>(
      z1, z2, p1, p2, out_b, out);
}